// Round 1
// baseline (1630.089 us; speedup 1.0000x reference)
//
#include <hip/hip_runtime.h>
#include <stdint.h>

// Problem constants: B=128, S=256, H=512
#define B_ 128
#define S_ 256
#define H_ 512

typedef __attribute__((ext_vector_type(4))) float f32x4;
typedef __attribute__((ext_vector_type(4))) int i32x4;
typedef __attribute__((ext_vector_type(2))) unsigned int u32x2;
typedef __attribute__((ext_vector_type(8))) __bf16 bf16x8;

// ---------- workspace layout (bytes) ----------
#define OFF_LOGITS 0          // 32768 f32  = 131072 B
#define OFF_G      131072     // 32768 f32  = 131072 B
#define OFF_RSR    262144     // 512 f32
#define OFF_RSH    264192     // 512 f32
#define OFF_CNT    266240     // 16 u32 group counters (+pad)
#define OFF_EX     270336     // 2 parities x 16 groups x 8 batches x 512 bf16 = 262144 B
#define OFF_CBUF   532480     // 128 x 512 f32 = 262144 B
#define OFF_BP     794624     // z1_w packed bf16 = 2097152 B
#define OFF_PB     2891776    // scan weights packed bf16 = 1048576 B
// total ~3.76 MB

__device__ __forceinline__ unsigned short f2bf(float f) {
  unsigned u = __builtin_bit_cast(unsigned, f);
  u += 0x7FFFu + ((u >> 16) & 1u);
  return (unsigned short)(u >> 16);
}
__device__ __forceinline__ float fast_sigmoid(float x) {
  return 1.0f / (1.0f + __expf(-x));
}
__device__ __forceinline__ float fast_tanh(float x) {
  return 1.0f - 2.0f / (__expf(2.0f * x) + 1.0f);
}

// ---------------------------------------------------------------------------
// Prep 1: pack z1_w (2048x512 f32) -> bf16, layout Bp[(k>>3)*512+n][k&7]
// so a 32-k-row chunk is a contiguous 32KB block whose 16B groups are exactly
// one MFMA B-fragment lane read.
// ---------------------------------------------------------------------------
__global__ void k_prep_bp(const float* __restrict__ z1w,
                          unsigned short* __restrict__ Bp) {
  int t = blockIdx.x * blockDim.x + threadIdx.x;  // < 2048*512
  int k = t >> 9, n = t & 511;
  Bp[((k >> 3) * 512 + n) * 8 + (k & 7)] = f2bf(z1w[t]);
}

// ---------------------------------------------------------------------------
// Prep 2: pack Ur,U into per-(mem,wave,ktile,lane) MFMA B-fragments.
// flat index t == destination index. mat = w>>1 (0=Ur,1=U), nt = w&1.
// ---------------------------------------------------------------------------
__global__ void k_prep_pb(const float* __restrict__ Ur,
                          const float* __restrict__ U,
                          unsigned short* __restrict__ PB) {
  int t = blockIdx.x * blockDim.x + threadIdx.x;  // < 524288
  int j = t & 7;
  int l = (t >> 3) & 63;
  int kt = (t >> 9) & 15;
  int w = (t >> 13) & 3;
  int mem = t >> 15;  // 0..15
  int k = kt * 32 + (l >> 4) * 8 + j;
  int n = mem * 32 + (w & 1) * 16 + (l & 15);
  const float* src = (w >> 1) ? U : Ur;
  PB[t] = f2bf(src[k * 512 + n]);
}

// ---------------------------------------------------------------------------
// Prep 3: row sums of Wr and W (the 'bsh,hk->bsh' einsum collapses to these)
// blocks 0..511 -> rs_r rows, 512..1023 -> rs_h rows. 256 threads.
// ---------------------------------------------------------------------------
__global__ void k_prep_rs(const float* __restrict__ Wr,
                          const float* __restrict__ W,
                          float* __restrict__ rsr, float* __restrict__ rsh) {
  __shared__ float red[4];
  int h2 = blockIdx.x;
  int t = threadIdx.x;
  const float* M = (h2 >= 512) ? W : Wr;
  int h = h2 & 511;
  float sv = M[h * 512 + t] + M[h * 512 + 256 + t];
#pragma unroll
  for (int mask = 1; mask < 64; mask <<= 1) sv += __shfl_xor(sv, mask, 64);
  if ((t & 63) == 0) red[t >> 6] = sv;
  __syncthreads();
  if (t == 0) {
    float tot = red[0] + red[1] + red[2] + red[3];
    ((h2 >= 512) ? rsh : rsr)[h] = tot;
  }
}

// ---------------------------------------------------------------------------
// Gate GEMM: logits[b,s] = sum_n tanh( (z @ z1_w)[b,s,n] + z1_b[n] ) * z2_w[n]
// z built on the fly from facts/q/m. Tile: M=64 (one batch), N=512 (full),
// K-loop 2048 in BK=32. 512 threads = 8 waves: wave = (mgrp in 2) x (ngrp in 4),
// each wave: 2 m-tiles x 8 n-tiles of 16x16x32 MFMA. Fused tanh+dot epilogue.
// ---------------------------------------------------------------------------
__global__ __launch_bounds__(512, 4) void k_gate(
    const float* __restrict__ facts, const float* __restrict__ questions,
    const float* __restrict__ prevM, const float* __restrict__ z1b,
    const float* __restrict__ z2w, const unsigned short* __restrict__ Bp,
    float* __restrict__ logits) {
  __shared__ float qS[512], mS[512], z1bS[512], z2wS[512];
  __shared__ unsigned short At[64 * 40];   // 64 rows, 32 bf16 + 8 pad (80B pitch)
  __shared__ unsigned short Bt[16384];     // 32KB: one BK=32 chunk of Bp
  __shared__ float lp[64 * 4];
  const int tid = threadIdx.x;
  const int row0 = blockIdx.x * 64;
  const int b = row0 >> 8;
  const int s0 = row0 & 255;
  qS[tid] = questions[b * 512 + tid];
  mS[tid] = prevM[b * 512 + tid];
  z1bS[tid] = z1b[tid];
  z2wS[tid] = z2w[tid];
  const int w = tid >> 6, l = tid & 63;
  const int mgrp = w & 1, ngrp = w >> 1;
  const int lm = l & 15, lk = l >> 4;
  f32x4 acc[2][8];
#pragma unroll
  for (int a = 0; a < 2; ++a)
#pragma unroll
    for (int i = 0; i < 8; ++i) acc[a][i] = (f32x4){0.f, 0.f, 0.f, 0.f};
  const int arow = tid >> 3, ac = tid & 7;
  const float* fbase = facts + ((size_t)(b * 256 + s0 + arow)) * 512 + ac * 4;

  for (int kb = 0; kb < 64; ++kb) {
    __syncthreads();  // protect LDS vs previous iteration's reads
    // ---- build A tile (64 rows x 32 k) in bf16 ----
    const int part = kb >> 4;          // 0: f*q, 1: f*m, 2: |f-q|, 3: |f-m|
    const int h0 = (kb & 15) * 32;
    f32x4 fv = *(const f32x4*)(fbase + h0);
    f32x4 ov = (part & 1) ? *(const f32x4*)&mS[h0 + ac * 4]
                          : *(const f32x4*)&qS[h0 + ac * 4];
    float z0, z1, z2, z3;
    if (part < 2) {
      z0 = fv[0] * ov[0]; z1 = fv[1] * ov[1];
      z2 = fv[2] * ov[2]; z3 = fv[3] * ov[3];
    } else {
      z0 = fabsf(fv[0] - ov[0]); z1 = fabsf(fv[1] - ov[1]);
      z2 = fabsf(fv[2] - ov[2]); z3 = fabsf(fv[3] - ov[3]);
    }
    unsigned p0 = (unsigned)f2bf(z0) | ((unsigned)f2bf(z1) << 16);
    unsigned p1 = (unsigned)f2bf(z2) | ((unsigned)f2bf(z3) << 16);
    u32x2 pk = {p0, p1};
    *(u32x2*)&At[arow * 40 + ac * 4] = pk;
    // ---- stage B tile (layout-preserving copy of 32KB Bp chunk) ----
    const char* bsrc = (const char*)Bp + (size_t)kb * 32768;
#pragma unroll
    for (int i = 0; i < 4; ++i)
      *(i32x4*)((char*)Bt + i * 8192 + tid * 16) =
          *(const i32x4*)(bsrc + i * 8192 + tid * 16);
    __syncthreads();
    // ---- fragments + MFMA ----
    bf16x8 af[2];
#pragma unroll
    for (int mi = 0; mi < 2; ++mi) {
      i32x4 av = *(const i32x4*)&At[((mgrp * 2 + mi) * 16 + lm) * 40 + lk * 8];
      af[mi] = __builtin_bit_cast(bf16x8, av);
    }
#pragma unroll
    for (int i = 0; i < 8; ++i) {
      const int nt = ngrp * 8 + i;
      i32x4 bv = *(const i32x4*)&Bt[lk * 4096 + (nt * 16 + lm) * 8];
      bf16x8 bf = __builtin_bit_cast(bf16x8, bv);
      acc[0][i] = __builtin_amdgcn_mfma_f32_16x16x32_bf16(af[0], bf, acc[0][i], 0, 0, 0);
      acc[1][i] = __builtin_amdgcn_mfma_f32_16x16x32_bf16(af[1], bf, acc[1][i], 0, 0, 0);
    }
  }
  // ---- fused epilogue: tanh + dot(z2_w), reduce to per-row logits ----
  float pr_[2][4];
#pragma unroll
  for (int mi = 0; mi < 2; ++mi)
#pragma unroll
    for (int r = 0; r < 4; ++r) pr_[mi][r] = 0.f;
#pragma unroll
  for (int i = 0; i < 8; ++i) {
    const int n_i = (ngrp * 8 + i) * 16 + lm;
    const float zb = z1bS[n_i], zw = z2wS[n_i];
#pragma unroll
    for (int mi = 0; mi < 2; ++mi)
#pragma unroll
      for (int r = 0; r < 4; ++r)
        pr_[mi][r] += fast_tanh(acc[mi][i][r] + zb) * zw;
  }
#pragma unroll
  for (int mask = 1; mask < 16; mask <<= 1)
#pragma unroll
    for (int mi = 0; mi < 2; ++mi)
#pragma unroll
      for (int r = 0; r < 4; ++r)
        pr_[mi][r] += __shfl_xor(pr_[mi][r], mask, 64);
  if (lm == 0) {
#pragma unroll
    for (int mi = 0; mi < 2; ++mi)
#pragma unroll
      for (int r = 0; r < 4; ++r)
        lp[((mgrp * 2 + mi) * 16 + lk * 4 + r) * 4 + ngrp] = pr_[mi][r];
  }
  __syncthreads();
  if (tid < 64)
    logits[row0 + tid] =
        lp[tid * 4] + lp[tid * 4 + 1] + lp[tid * 4 + 2] + lp[tid * 4 + 3];
}

// ---------------------------------------------------------------------------
// Softmax over S per batch (z2_b dropped: softmax shift-invariant, exact)
// ---------------------------------------------------------------------------
__global__ void k_softmax(const float* __restrict__ logits,
                          float* __restrict__ G) {
  __shared__ float red[4], red2[4];
  int b = blockIdx.x, t = threadIdx.x;
  float v = logits[b * 256 + t];
  float mx = v;
#pragma unroll
  for (int mask = 1; mask < 64; mask <<= 1)
    mx = fmaxf(mx, __shfl_xor(mx, mask, 64));
  if ((t & 63) == 0) red[t >> 6] = mx;
  __syncthreads();
  mx = fmaxf(fmaxf(red[0], red[1]), fmaxf(red[2], red[3]));
  float e = __expf(v - mx);
  float sm = e;
#pragma unroll
  for (int mask = 1; mask < 64; mask <<= 1) sm += __shfl_xor(sm, mask, 64);
  if ((t & 63) == 0) red2[t >> 6] = sm;
  __syncthreads();
  sm = red2[0] + red2[1] + red2[2] + red2[3];
  G[b * 256 + t] = e / sm;
}

// ---------------------------------------------------------------------------
// Scan: 16 groups x 16 member-WGs. Group g owns batches g*8..g*8+7; member
// 'mem' owns n-slice [mem*32, mem*32+32). Weights (Ur,U) live in VGPRs as
// pre-packed MFMA B-fragments for the whole kernel. Per step:
//   mfma (M=16 padded: rows 0..7 = C for 8 batches) -> elementwise r/h~/C
//   -> publish bf16 C slice to global (agent atomics) -> group counter barrier
//   -> gather full C into A-LDS -> next step. EX double-buffered on step parity.
// ---------------------------------------------------------------------------
__global__ __launch_bounds__(256, 1) void k_scan(
    const float* __restrict__ facts, const float* __restrict__ Gm,
    const unsigned short* __restrict__ PB, const float* __restrict__ rsr,
    const float* __restrict__ rsh, const float* __restrict__ br,
    const float* __restrict__ bur, const float* __restrict__ bw,
    const float* __restrict__ bu, unsigned int* __restrict__ EX,
    unsigned int* __restrict__ cnt, float* __restrict__ Cb) {
  __shared__ unsigned short A[16 * 520];  // 16 rows x 512 bf16, 1040B pitch
  __shared__ float outb[4 * 256];         // [w][row16][col16]
  const int tid = threadIdx.x;
  const int g = blockIdx.x & 15;    // group (same XCD under %8 round-robin)
  const int mem = blockIdx.x >> 4;  // member / n-slice
  const int w = tid >> 6, l = tid & 63;
  const int lm = l & 15, lk = l >> 4;
  // zero A (rows 8..15 stay zero forever: M-padding)
  for (int i = tid; i < 16 * 520 / 2; i += 256) ((int*)A)[i] = 0;
  // weight fragments: 16 k-tiles for this wave's (mat = w>>1, nt = w&1)
  i32x4 bfr[16];
  const char* pb = (const char*)PB + (size_t)(mem * 4 + w) * 16384;
#pragma unroll
  for (int kt = 0; kt < 16; ++kt)
    bfr[kt] = *(const i32x4*)(pb + kt * 1024 + l * 16);
  // per-thread elementwise lane: (bb, nl)
  const int bb = tid >> 5, nl = tid & 31;
  const int n = mem * 32 + nl;
  const int batch = g * 8 + bb;
  const float c_rsr = rsr[n], c_br = br[n];
  const float c_rsh = rsh[n], c_bw = bw[n];
  const float c_bur = bur[n], c_bu = bu[n];
  const float* fptr = facts + (size_t)batch * 256 * 512 + n;
  const float* gptr = Gm + batch * 256;
  const int nt_t = nl >> 4, col_t = nl & 15;
  float C = 0.0f;
  __syncthreads();

  for (int s = 0; s < 256; ++s) {
    const float fct = fptr[(size_t)s * 512];  // prefetch early
    const float gval = gptr[s];
    // ---- matvec: (C @ Ur | C @ U) slice via MFMA, two ILP chains ----
    f32x4 acc0 = (f32x4){0.f, 0.f, 0.f, 0.f};
    f32x4 acc1 = (f32x4){0.f, 0.f, 0.f, 0.f};
#pragma unroll
    for (int kt = 0; kt < 16; ++kt) {
      i32x4 av = *(const i32x4*)&A[lm * 520 + kt * 32 + lk * 8];
      bf16x8 afv = __builtin_bit_cast(bf16x8, av);
      bf16x8 bfv = __builtin_bit_cast(bf16x8, bfr[kt]);
      if (kt & 1)
        acc1 = __builtin_amdgcn_mfma_f32_16x16x32_bf16(afv, bfv, acc1, 0, 0, 0);
      else
        acc0 = __builtin_amdgcn_mfma_f32_16x16x32_bf16(afv, bfv, acc0, 0, 0, 0);
    }
    f32x4 accs = acc0 + acc1;
#pragma unroll
    for (int r = 0; r < 4; ++r)
      outb[w * 256 + (lk * 4 + r) * 16 + lm] = accs[r];
    __syncthreads();
    // ---- elementwise update (thread owns (bb, n)) ----
    const float uro = outb[nt_t * 256 + bb * 16 + col_t];        // (C@Ur)[bb][n]
    const float uuo = outb[(2 + nt_t) * 256 + bb * 16 + col_t];  // (C@U)[bb][n]
    const float pr = fct * c_rsr + c_br;
    const float ph = fct * c_rsh + c_bw;
    const float r_ = fast_sigmoid(pr + uro + c_bur);
    const float ht = fast_tanh(ph + r_ * (uuo + c_bu));
    C = gval * ht + (1.0f - gval) * C;
    // ---- publish C slice (bf16, device-scope) ----
    unsigned myb = f2bf(C);
    unsigned ob = (unsigned)__shfl_xor((int)myb, 1, 64);
    if ((tid & 1) == 0) {
      unsigned word = myb | (ob << 16);
      unsigned didx =
          ((unsigned)(s & 1) * 16 + g) * 2048 + bb * 256 + ((unsigned)n >> 1);
      __hip_atomic_store(EX + didx, word, __ATOMIC_RELAXED,
                         __HIP_MEMORY_SCOPE_AGENT);
    }
    __syncthreads();  // drains vmcnt per thread before barrier
    if (tid == 0) {
      __hip_atomic_fetch_add(cnt + g, 1u, __ATOMIC_RELAXED,
                             __HIP_MEMORY_SCOPE_AGENT);
      const unsigned target = 16u * (unsigned)(s + 1);
      int guard = 0;
      while (__hip_atomic_load(cnt + g, __ATOMIC_RELAXED,
                               __HIP_MEMORY_SCOPE_AGENT) < target) {
        __builtin_amdgcn_s_sleep(1);
        if (++guard > (1 << 28)) break;  // hang-safety bailout
      }
    }
    __syncthreads();
    // ---- gather full new C (8 x 512 bf16) into A-LDS rows 0..7 ----
    const unsigned base = ((unsigned)(s & 1) * 16 + g) * 2048;
#pragma unroll
    for (int i = 0; i < 16; ++i) {
      int d = tid * 16 + i;  // 4096 dwords total
      unsigned word = __hip_atomic_load(EX + base + d, __ATOMIC_RELAXED,
                                        __HIP_MEMORY_SCOPE_AGENT);
      int bbr = d >> 8, ndw = d & 255;
      *(unsigned*)((char*)A + bbr * 1040 + ndw * 4) = word;
    }
    __syncthreads();
  }
  Cb[(size_t)batch * 512 + n] = C;  // final state, f32
}

// ---------------------------------------------------------------------------
// Final: out[b] = relu([prevM | C | questions] @ nm_w + nm_b). 2 batches/WG.
// ---------------------------------------------------------------------------
__global__ __launch_bounds__(512) void k_final(
    const float* __restrict__ prevM, const float* __restrict__ questions,
    const float* __restrict__ Cb, const float* __restrict__ nmw,
    const float* __restrict__ nmb, float* __restrict__ out) {
  __shared__ float cc[2][1536];
  const int t = threadIdx.x;
  const int b0 = blockIdx.x * 2;
  for (int i = t; i < 1536; i += 512) {
#pragma unroll
    for (int bi = 0; bi < 2; ++bi) {
      int bbx = b0 + bi;
      float v;
      if (i < 512) v = prevM[bbx * 512 + i];
      else if (i < 1024) v = Cb[bbx * 512 + i - 512];
      else v = questions[bbx * 512 + i - 1024];
      cc[bi][i] = v;
    }
  }
  __syncthreads();
  const int h = t;
  float a0 = nmb[h], a1 = nmb[h];
#pragma unroll 4
  for (int f = 0; f < 1536; ++f) {
    float wv = nmw[f * 512 + h];
    a0 = fmaf(cc[0][f], wv, a0);
    a1 = fmaf(cc[1][f], wv, a1);
  }
  out[(size_t)b0 * 512 + h] = fmaxf(a0, 0.f);
  out[(size_t)(b0 + 1) * 512 + h] = fmaxf(a1, 0.f);
}

// ---------------------------------------------------------------------------
extern "C" void kernel_launch(void* const* d_in, const int* in_sizes, int n_in,
                              void* d_out, int out_size, void* d_ws,
                              size_t ws_size, hipStream_t stream) {
  const float* facts     = (const float*)d_in[0];
  const float* questions = (const float*)d_in[1];
  const float* prevM     = (const float*)d_in[2];
  const float* z1w       = (const float*)d_in[3];
  const float* z1b       = (const float*)d_in[4];
  const float* z2w       = (const float*)d_in[5];
  // d_in[6] = z2_b: softmax shift-invariant, unused (exact)
  const float* Wr        = (const float*)d_in[7];
  const float* br        = (const float*)d_in[8];
  const float* Ur        = (const float*)d_in[9];
  const float* bur       = (const float*)d_in[10];
  const float* W         = (const float*)d_in[11];
  const float* bw        = (const float*)d_in[12];
  const float* U         = (const float*)d_in[13];
  const float* bu        = (const float*)d_in[14];
  const float* nmw       = (const float*)d_in[15];
  const float* nmb       = (const float*)d_in[16];

  char* ws = (char*)d_ws;
  float* logits        = (float*)(ws + OFF_LOGITS);
  float* G             = (float*)(ws + OFF_G);
  float* rsr           = (float*)(ws + OFF_RSR);
  float* rsh           = (float*)(ws + OFF_RSH);
  unsigned* cnt        = (unsigned*)(ws + OFF_CNT);
  unsigned* EX         = (unsigned*)(ws + OFF_EX);
  float* Cb            = (float*)(ws + OFF_CBUF);
  unsigned short* Bp   = (unsigned short*)(ws + OFF_BP);
  unsigned short* PB   = (unsigned short*)(ws + OFF_PB);

  hipMemsetAsync(cnt, 0, 64, stream);
  k_prep_bp<<<2048, 512, 0, stream>>>(z1w, Bp);
  k_prep_pb<<<1024, 512, 0, stream>>>(Ur, U, PB);
  k_prep_rs<<<1024, 256, 0, stream>>>(Wr, W, rsr, rsh);
  k_gate<<<512, 512, 0, stream>>>(facts, questions, prevM, z1b, z2w, Bp, logits);
  k_softmax<<<128, 256, 0, stream>>>(logits, G);
  k_scan<<<256, 256, 0, stream>>>(facts, G, PB, rsr, rsh, br, bur, bw, bu, EX,
                                  cnt, Cb);
  k_final<<<64, 512, 0, stream>>>(prevM, questions, Cb, nmw, nmb, (float*)d_out);
}

// Round 2
// 1619.037 us; speedup vs baseline: 1.0068x; 1.0068x over previous
//
#include <hip/hip_runtime.h>
#include <stdint.h>

// Problem constants: B=128, S=256, H=512
#define B_ 128
#define S_ 256
#define H_ 512

typedef __attribute__((ext_vector_type(4))) float f32x4;
typedef __attribute__((ext_vector_type(4))) int i32x4;
typedef __attribute__((ext_vector_type(2))) unsigned int u32x2;
typedef __attribute__((ext_vector_type(8))) __bf16 bf16x8;

// ---------- workspace layout (bytes) ----------
#define OFF_G      0          // 32768 f32 = 131072 B
#define OFF_RSR    131072     // 512 f32
#define OFF_RSH    133120     // 512 f32
#define OFF_EX     135168     // 2 parity x 16 groups x 8 batches x 512 dwords = 524288 B
#define OFF_CBUF   659456     // 128 x 512 f32 = 262144 B
#define OFF_LOGITS 659456     // alias: logits dead before Cb is written (scan end)
#define OFF_BP     921600     // z1_w packed bf16 = 2097152 B
#define OFF_PB     3018752    // scan weights packed bf16 = 1048576 B
// total ~3.88 MB

__device__ __forceinline__ unsigned short f2bf(float f) {
  unsigned u = __builtin_bit_cast(unsigned, f);
  u += 0x7FFFu + ((u >> 16) & 1u);
  return (unsigned short)(u >> 16);
}
__device__ __forceinline__ float fast_sigmoid(float x) {
  return 1.0f / (1.0f + __expf(-x));
}
__device__ __forceinline__ float fast_tanh(float x) {
  return 1.0f - 2.0f / (__expf(2.0f * x) + 1.0f);
}

// ---------------------------------------------------------------------------
// Prep 1: pack z1_w (2048x512 f32) -> bf16, layout Bp[(k>>3)*512+n][k&7]
// ---------------------------------------------------------------------------
__global__ void k_prep_bp(const float* __restrict__ z1w,
                          unsigned short* __restrict__ Bp) {
  int t = blockIdx.x * blockDim.x + threadIdx.x;  // < 2048*512
  int k = t >> 9, n = t & 511;
  Bp[((k >> 3) * 512 + n) * 8 + (k & 7)] = f2bf(z1w[t]);
}

// ---------------------------------------------------------------------------
// Prep 2: pack Ur,U into per-(mem,wave,ktile,lane) MFMA B-fragments.
// ---------------------------------------------------------------------------
__global__ void k_prep_pb(const float* __restrict__ Ur,
                          const float* __restrict__ U,
                          unsigned short* __restrict__ PB) {
  int t = blockIdx.x * blockDim.x + threadIdx.x;  // < 524288
  int j = t & 7;
  int l = (t >> 3) & 63;
  int kt = (t >> 9) & 15;
  int w = (t >> 13) & 3;
  int mem = t >> 15;  // 0..15
  int k = kt * 32 + (l >> 4) * 8 + j;
  int n = mem * 32 + (w & 1) * 16 + (l & 15);
  const float* src = (w >> 1) ? U : Ur;
  PB[t] = f2bf(src[k * 512 + n]);
}

// ---------------------------------------------------------------------------
// Prep 3: row sums of Wr and W ('bsh,hk->bsh' collapses to these)
// ---------------------------------------------------------------------------
__global__ void k_prep_rs(const float* __restrict__ Wr,
                          const float* __restrict__ W,
                          float* __restrict__ rsr, float* __restrict__ rsh) {
  __shared__ float red[4];
  int h2 = blockIdx.x;
  int t = threadIdx.x;
  const float* M = (h2 >= 512) ? W : Wr;
  int h = h2 & 511;
  float sv = M[h * 512 + t] + M[h * 512 + 256 + t];
#pragma unroll
  for (int mask = 1; mask < 64; mask <<= 1) sv += __shfl_xor(sv, mask, 64);
  if ((t & 63) == 0) red[t >> 6] = sv;
  __syncthreads();
  if (t == 0) {
    float tot = red[0] + red[1] + red[2] + red[3];
    ((h2 >= 512) ? rsh : rsr)[h] = tot;
  }
}

// ---------------------------------------------------------------------------
// Gate GEMM + fused tanh/dot epilogue (unchanged from R1 — not the bottleneck)
// ---------------------------------------------------------------------------
__global__ __launch_bounds__(512, 4) void k_gate(
    const float* __restrict__ facts, const float* __restrict__ questions,
    const float* __restrict__ prevM, const float* __restrict__ z1b,
    const float* __restrict__ z2w, const unsigned short* __restrict__ Bp,
    float* __restrict__ logits) {
  __shared__ float qS[512], mS[512], z1bS[512], z2wS[512];
  __shared__ unsigned short At[64 * 40];
  __shared__ unsigned short Bt[16384];
  __shared__ float lp[64 * 4];
  const int tid = threadIdx.x;
  const int row0 = blockIdx.x * 64;
  const int b = row0 >> 8;
  const int s0 = row0 & 255;
  qS[tid] = questions[b * 512 + tid];
  mS[tid] = prevM[b * 512 + tid];
  z1bS[tid] = z1b[tid];
  z2wS[tid] = z2w[tid];
  const int w = tid >> 6, l = tid & 63;
  const int mgrp = w & 1, ngrp = w >> 1;
  const int lm = l & 15, lk = l >> 4;
  f32x4 acc[2][8];
#pragma unroll
  for (int a = 0; a < 2; ++a)
#pragma unroll
    for (int i = 0; i < 8; ++i) acc[a][i] = (f32x4){0.f, 0.f, 0.f, 0.f};
  const int arow = tid >> 3, ac = tid & 7;
  const float* fbase = facts + ((size_t)(b * 256 + s0 + arow)) * 512 + ac * 4;

  for (int kb = 0; kb < 64; ++kb) {
    __syncthreads();
    const int part = kb >> 4;          // 0: f*q, 1: f*m, 2: |f-q|, 3: |f-m|
    const int h0 = (kb & 15) * 32;
    f32x4 fv = *(const f32x4*)(fbase + h0);
    f32x4 ov = (part & 1) ? *(const f32x4*)&mS[h0 + ac * 4]
                          : *(const f32x4*)&qS[h0 + ac * 4];
    float z0, z1, z2, z3;
    if (part < 2) {
      z0 = fv[0] * ov[0]; z1 = fv[1] * ov[1];
      z2 = fv[2] * ov[2]; z3 = fv[3] * ov[3];
    } else {
      z0 = fabsf(fv[0] - ov[0]); z1 = fabsf(fv[1] - ov[1]);
      z2 = fabsf(fv[2] - ov[2]); z3 = fabsf(fv[3] - ov[3]);
    }
    unsigned p0 = (unsigned)f2bf(z0) | ((unsigned)f2bf(z1) << 16);
    unsigned p1 = (unsigned)f2bf(z2) | ((unsigned)f2bf(z3) << 16);
    u32x2 pk = {p0, p1};
    *(u32x2*)&At[arow * 40 + ac * 4] = pk;
    const char* bsrc = (const char*)Bp + (size_t)kb * 32768;
#pragma unroll
    for (int i = 0; i < 4; ++i)
      *(i32x4*)((char*)Bt + i * 8192 + tid * 16) =
          *(const i32x4*)(bsrc + i * 8192 + tid * 16);
    __syncthreads();
    bf16x8 af[2];
#pragma unroll
    for (int mi = 0; mi < 2; ++mi) {
      i32x4 av = *(const i32x4*)&At[((mgrp * 2 + mi) * 16 + lm) * 40 + lk * 8];
      af[mi] = __builtin_bit_cast(bf16x8, av);
    }
#pragma unroll
    for (int i = 0; i < 8; ++i) {
      const int nt = ngrp * 8 + i;
      i32x4 bv = *(const i32x4*)&Bt[lk * 4096 + (nt * 16 + lm) * 8];
      bf16x8 bf = __builtin_bit_cast(bf16x8, bv);
      acc[0][i] = __builtin_amdgcn_mfma_f32_16x16x32_bf16(af[0], bf, acc[0][i], 0, 0, 0);
      acc[1][i] = __builtin_amdgcn_mfma_f32_16x16x32_bf16(af[1], bf, acc[1][i], 0, 0, 0);
    }
  }
  float pr_[2][4];
#pragma unroll
  for (int mi = 0; mi < 2; ++mi)
#pragma unroll
    for (int r = 0; r < 4; ++r) pr_[mi][r] = 0.f;
#pragma unroll
  for (int i = 0; i < 8; ++i) {
    const int n_i = (ngrp * 8 + i) * 16 + lm;
    const float zb = z1bS[n_i], zw = z2wS[n_i];
#pragma unroll
    for (int mi = 0; mi < 2; ++mi)
#pragma unroll
      for (int r = 0; r < 4; ++r)
        pr_[mi][r] += fast_tanh(acc[mi][i][r] + zb) * zw;
  }
#pragma unroll
  for (int mask = 1; mask < 16; mask <<= 1)
#pragma unroll
    for (int mi = 0; mi < 2; ++mi)
#pragma unroll
      for (int r = 0; r < 4; ++r)
        pr_[mi][r] += __shfl_xor(pr_[mi][r], mask, 64);
  if (lm == 0) {
#pragma unroll
    for (int mi = 0; mi < 2; ++mi)
#pragma unroll
      for (int r = 0; r < 4; ++r)
        lp[((mgrp * 2 + mi) * 16 + lk * 4 + r) * 4 + ngrp] = pr_[mi][r];
  }
  __syncthreads();
  if (tid < 64)
    logits[row0 + tid] =
        lp[tid * 4] + lp[tid * 4 + 1] + lp[tid * 4 + 2] + lp[tid * 4 + 3];
}

// ---------------------------------------------------------------------------
// Softmax over S per batch (z2_b dropped: shift-invariant, exact)
// ---------------------------------------------------------------------------
__global__ void k_softmax(const float* __restrict__ logits,
                          float* __restrict__ G) {
  __shared__ float red[4], red2[4];
  int b = blockIdx.x, t = threadIdx.x;
  float v = logits[b * 256 + t];
  float mx = v;
#pragma unroll
  for (int mask = 1; mask < 64; mask <<= 1)
    mx = fmaxf(mx, __shfl_xor(mx, mask, 64));
  if ((t & 63) == 0) red[t >> 6] = mx;
  __syncthreads();
  mx = fmaxf(fmaxf(red[0], red[1]), fmaxf(red[2], red[3]));
  float e = __expf(v - mx);
  float sm = e;
#pragma unroll
  for (int mask = 1; mask < 64; mask <<= 1) sm += __shfl_xor(sm, mask, 64);
  if ((t & 63) == 0) red2[t >> 6] = sm;
  __syncthreads();
  sm = red2[0] + red2[1] + red2[2] + red2[3];
  G[b * 256 + t] = e / sm;
}

// ---------------------------------------------------------------------------
// Scan v2: counter barrier REMOVED. Exchange words are self-flagging:
//   word = bf16(C)<<16 | (s+1).  Consumers poll the data directly with
// relaxed agent-scope loads (no RMW anywhere). Double-buffered on parity
// (WAR-safe: a producer at step s+2 implies all consumers finished step s).
// Own-slice C values are written straight into A-LDS, skipping global.
// 0xAA poison can't alias a tag (0xAAAA not in [1,256]), so no init needed.
// ---------------------------------------------------------------------------
__global__ __launch_bounds__(256, 1) void k_scan(
    const float* __restrict__ facts, const float* __restrict__ Gm,
    const unsigned short* __restrict__ PB, const float* __restrict__ rsr,
    const float* __restrict__ rsh, const float* __restrict__ br,
    const float* __restrict__ bur, const float* __restrict__ bw,
    const float* __restrict__ bu, unsigned int* __restrict__ EX,
    float* __restrict__ Cb) {
  __shared__ unsigned short A[16 * 520];  // 16 rows x 512 bf16, 1040B pitch
  __shared__ float outb[4 * 256];         // [w][row16][col16]
  const int tid = threadIdx.x;
  const int g = blockIdx.x & 15;    // group
  const int mem = blockIdx.x >> 4;  // member / n-slice
  const int w = tid >> 6, l = tid & 63;
  const int lm = l & 15, lk = l >> 4;
  // zero A (rows 8..15 stay zero forever: M-padding)
  for (int i = tid; i < 16 * 520 / 2; i += 256) ((int*)A)[i] = 0;
  // weight fragments resident in VGPRs for the whole kernel
  i32x4 bfr[16];
  const char* pb = (const char*)PB + (size_t)(mem * 4 + w) * 16384;
#pragma unroll
  for (int kt = 0; kt < 16; ++kt)
    bfr[kt] = *(const i32x4*)(pb + kt * 1024 + l * 16);
  // per-thread elementwise lane: (bb, nl)
  const int bb = tid >> 5, nl = tid & 31;
  const int n = mem * 32 + nl;
  const int batch = g * 8 + bb;
  const float c_rsr = rsr[n], c_br = br[n];
  const float c_rsh = rsh[n], c_bw = bw[n];
  const float c_bur = bur[n], c_bu = bu[n];
  const float* fptr = facts + (size_t)batch * 256 * 512 + n;
  const float* gptr = Gm + batch * 256;
  const int nt_t = nl >> 4, col_t = nl & 15;
  // gather mapping: this thread polls 16 consecutive dwords of the exchange
  const int gd = tid * 16;       // 0..4095 (8 rows x 512 cols)
  const int grow = gd >> 9;      // batch row 0..7
  const int gcol = gd & 511;     // col base (16-aligned; run stays in 1 slice)
  const bool own = ((gcol >> 5) == mem);  // own slice arrives via LDS directly
  unsigned short* gA = (unsigned short*)((char*)A + grow * 1040 + gcol * 2);
  float C = 0.0f;
  __syncthreads();

  for (int s = 0; s < 256; ++s) {
    const float fct = fptr[(size_t)s * 512];
    const float gval = gptr[s];
    // ---- matvec: (C @ Ur | C @ U) slice via MFMA, two ILP chains ----
    f32x4 acc0 = (f32x4){0.f, 0.f, 0.f, 0.f};
    f32x4 acc1 = (f32x4){0.f, 0.f, 0.f, 0.f};
#pragma unroll
    for (int kt = 0; kt < 16; ++kt) {
      i32x4 av = *(const i32x4*)&A[lm * 520 + kt * 32 + lk * 8];
      bf16x8 afv = __builtin_bit_cast(bf16x8, av);
      bf16x8 bfv = __builtin_bit_cast(bf16x8, bfr[kt]);
      if (kt & 1)
        acc1 = __builtin_amdgcn_mfma_f32_16x16x32_bf16(afv, bfv, acc1, 0, 0, 0);
      else
        acc0 = __builtin_amdgcn_mfma_f32_16x16x32_bf16(afv, bfv, acc0, 0, 0, 0);
    }
    f32x4 accs = acc0 + acc1;
#pragma unroll
    for (int r = 0; r < 4; ++r)
      outb[w * 256 + (lk * 4 + r) * 16 + lm] = accs[r];
    __syncthreads();  // also orders: MFMA A-reads done before A-writes below
    // ---- elementwise update (thread owns (bb, n)) ----
    const float uro = outb[nt_t * 256 + bb * 16 + col_t];
    const float uuo = outb[(2 + nt_t) * 256 + bb * 16 + col_t];
    const float pr = fct * c_rsr + c_br;
    const float ph = fct * c_rsh + c_bw;
    const float r_ = fast_sigmoid(pr + uro + c_bur);
    const float ht = fast_tanh(ph + r_ * (uuo + c_bu));
    C = gval * ht + (1.0f - gval) * C;
    const unsigned myb = (unsigned)f2bf(C);
    // own slice straight into A-LDS (never round-trips through global)
    *(unsigned short*)((char*)A + bb * 1040 + n * 2) = (unsigned short)myb;
    // publish self-flagging word for the other 15 members
    const unsigned tag = (unsigned)(s + 1);
    const unsigned base = ((unsigned)(s & 1) * 16 + (unsigned)g) * 4096;
    __hip_atomic_store(EX + base + (unsigned)bb * 512 + (unsigned)n,
                       (myb << 16) | tag, __ATOMIC_RELAXED,
                       __HIP_MEMORY_SCOPE_AGENT);
    // ---- poll-gather remote slices (tag == s+1 validates the payload) ----
    if (!own) {
      const unsigned* src = EX + base + (unsigned)gd;
      unsigned done = 0;
      int guard = 0;
      while (done != 0xFFFFu) {
#pragma unroll
        for (int i = 0; i < 16; ++i) {
          if (!((done >> i) & 1u)) {
            unsigned wv = __hip_atomic_load(src + i, __ATOMIC_RELAXED,
                                            __HIP_MEMORY_SCOPE_AGENT);
            if ((wv & 0xFFFFu) == tag) {
              gA[i] = (unsigned short)(wv >> 16);
              done |= (1u << i);
            }
          }
        }
        if (++guard > (1 << 20)) break;  // hang-safety bailout
      }
    }
    __syncthreads();  // A fully assembled for next step
  }
  Cb[(size_t)batch * 512 + n] = C;  // final state, f32
}

// ---------------------------------------------------------------------------
// Final: out[b] = relu([prevM | C | questions] @ nm_w + nm_b). 2 batches/WG.
// ---------------------------------------------------------------------------
__global__ __launch_bounds__(512) void k_final(
    const float* __restrict__ prevM, const float* __restrict__ questions,
    const float* __restrict__ Cb, const float* __restrict__ nmw,
    const float* __restrict__ nmb, float* __restrict__ out) {
  __shared__ float cc[2][1536];
  const int t = threadIdx.x;
  const int b0 = blockIdx.x * 2;
  for (int i = t; i < 1536; i += 512) {
#pragma unroll
    for (int bi = 0; bi < 2; ++bi) {
      int bbx = b0 + bi;
      float v;
      if (i < 512) v = prevM[bbx * 512 + i];
      else if (i < 1024) v = Cb[bbx * 512 + i - 512];
      else v = questions[bbx * 512 + i - 1024];
      cc[bi][i] = v;
    }
  }
  __syncthreads();
  const int h = t;
  float a0 = nmb[h], a1 = nmb[h];
#pragma unroll 4
  for (int f = 0; f < 1536; ++f) {
    float wv = nmw[f * 512 + h];
    a0 = fmaf(cc[0][f], wv, a0);
    a1 = fmaf(cc[1][f], wv, a1);
  }
  out[(size_t)b0 * 512 + h] = fmaxf(a0, 0.f);
  out[(size_t)(b0 + 1) * 512 + h] = fmaxf(a1, 0.f);
}

// ---------------------------------------------------------------------------
extern "C" void kernel_launch(void* const* d_in, const int* in_sizes, int n_in,
                              void* d_out, int out_size, void* d_ws,
                              size_t ws_size, hipStream_t stream) {
  const float* facts     = (const float*)d_in[0];
  const float* questions = (const float*)d_in[1];
  const float* prevM     = (const float*)d_in[2];
  const float* z1w       = (const float*)d_in[3];
  const float* z1b       = (const float*)d_in[4];
  const float* z2w       = (const float*)d_in[5];
  // d_in[6] = z2_b: softmax shift-invariant, unused (exact)
  const float* Wr        = (const float*)d_in[7];
  const float* br        = (const float*)d_in[8];
  const float* Ur        = (const float*)d_in[9];
  const float* bur       = (const float*)d_in[10];
  const float* W         = (const float*)d_in[11];
  const float* bw        = (const float*)d_in[12];
  const float* U         = (const float*)d_in[13];
  const float* bu        = (const float*)d_in[14];
  const float* nmw       = (const float*)d_in[15];
  const float* nmb       = (const float*)d_in[16];

  char* ws = (char*)d_ws;
  float* G             = (float*)(ws + OFF_G);
  float* rsr           = (float*)(ws + OFF_RSR);
  float* rsh           = (float*)(ws + OFF_RSH);
  unsigned* EX         = (unsigned*)(ws + OFF_EX);
  float* Cb            = (float*)(ws + OFF_CBUF);
  float* logits        = (float*)(ws + OFF_LOGITS);
  unsigned short* Bp   = (unsigned short*)(ws + OFF_BP);
  unsigned short* PB   = (unsigned short*)(ws + OFF_PB);

  k_prep_bp<<<2048, 512, 0, stream>>>(z1w, Bp);
  k_prep_pb<<<1024, 512, 0, stream>>>(Ur, U, PB);
  k_prep_rs<<<1024, 256, 0, stream>>>(Wr, W, rsr, rsh);
  k_gate<<<512, 512, 0, stream>>>(facts, questions, prevM, z1b, z2w, Bp, logits);
  k_softmax<<<128, 256, 0, stream>>>(logits, G);
  k_scan<<<256, 256, 0, stream>>>(facts, G, PB, rsr, rsh, br, bur, bw, bu, EX, Cb);
  k_final<<<64, 512, 0, stream>>>(prevM, questions, Cb, nmw, nmb, (float*)d_out);
}

// Round 3
// 1033.101 us; speedup vs baseline: 1.5779x; 1.5672x over previous
//
#include <hip/hip_runtime.h>
#include <stdint.h>

// Problem constants: B=128, S=256, H=512
#define B_ 128
#define S_ 256
#define H_ 512

typedef __attribute__((ext_vector_type(4))) float f32x4;
typedef __attribute__((ext_vector_type(4))) int i32x4;
typedef __attribute__((ext_vector_type(2))) unsigned int u32x2;
typedef __attribute__((ext_vector_type(8))) __bf16 bf16x8;
typedef unsigned long long u64;

// ---------- workspace layout (bytes) ----------
#define OFF_G      0          // 32768 f32 = 131072 B
#define OFF_RSR    131072     // 512 f32
#define OFF_RSH    133120     // 512 f32
#define OFF_FLG    135168     // 64 u32 flags (+pad to 4 KiB)
#define OFF_EX     139264     // 2 parity x 8 groups x 2048 u64 = 262144 B
#define OFF_CBUF   401408     // 128 x 512 f32 = 262144 B
#define OFF_LOGITS 401408     // alias: logits dead before Cb written
#define OFF_BP     663552     // z1_w packed bf16 = 2097152 B
#define OFF_PB     2760704    // scan weights packed bf16 = 1048576 B
// total ~3.81 MB

__device__ __forceinline__ unsigned short f2bf(float f) {
  unsigned u = __builtin_bit_cast(unsigned, f);
  u += 0x7FFFu + ((u >> 16) & 1u);
  return (unsigned short)(u >> 16);
}
__device__ __forceinline__ float fast_sigmoid(float x) {
  return 1.0f / (1.0f + __expf(-x));
}
__device__ __forceinline__ float fast_tanh(float x) {
  return 1.0f - 2.0f / (__expf(2.0f * x) + 1.0f);
}

// ---------------------------------------------------------------------------
// Prep 1: pack z1_w (2048x512 f32) -> bf16, layout Bp[(k>>3)*512+n][k&7]
// ---------------------------------------------------------------------------
__global__ void k_prep_bp(const float* __restrict__ z1w,
                          unsigned short* __restrict__ Bp) {
  int t = blockIdx.x * blockDim.x + threadIdx.x;  // < 2048*512
  int k = t >> 9, n = t & 511;
  Bp[((k >> 3) * 512 + n) * 8 + (k & 7)] = f2bf(z1w[t]);
}

// ---------------------------------------------------------------------------
// Prep 2: pack Ur,U into per-(mem 0..7, wave 0..7, ktile 0..15, lane) MFMA
// B-fragments. mat = w>>2 (0=Ur,1=U), nt = w&3; n = mem*64 + nt*16 + (l&15).
// ---------------------------------------------------------------------------
__global__ void k_prep_pb(const float* __restrict__ Ur,
                          const float* __restrict__ U,
                          unsigned short* __restrict__ PB) {
  int t = blockIdx.x * blockDim.x + threadIdx.x;  // < 524288
  int j = t & 7;
  int l = (t >> 3) & 63;
  int kt = (t >> 9) & 15;
  int w = (t >> 13) & 7;
  int mem = t >> 16;  // 0..7
  int k = kt * 32 + ((l >> 4) & 3) * 8 + j;
  int n = mem * 64 + (w & 3) * 16 + (l & 15);
  const float* src = (w >> 2) ? U : Ur;
  PB[t] = f2bf(src[k * 512 + n]);
}

// ---------------------------------------------------------------------------
// Prep 3: row sums of Wr and W ('bsh,hk->bsh' collapses to these)
// ---------------------------------------------------------------------------
__global__ void k_prep_rs(const float* __restrict__ Wr,
                          const float* __restrict__ W,
                          float* __restrict__ rsr, float* __restrict__ rsh) {
  __shared__ float red[4];
  int h2 = blockIdx.x;
  int t = threadIdx.x;
  const float* M = (h2 >= 512) ? W : Wr;
  int h = h2 & 511;
  float sv = M[h * 512 + t] + M[h * 512 + 256 + t];
#pragma unroll
  for (int mask = 1; mask < 64; mask <<= 1) sv += __shfl_xor(sv, mask, 64);
  if ((t & 63) == 0) red[t >> 6] = sv;
  __syncthreads();
  if (t == 0) {
    float tot = red[0] + red[1] + red[2] + red[3];
    ((h2 >= 512) ? rsh : rsr)[h] = tot;
  }
}

// ---------------------------------------------------------------------------
// Gate GEMM + fused tanh/dot epilogue (unchanged — not the bottleneck)
// ---------------------------------------------------------------------------
__global__ __launch_bounds__(512, 4) void k_gate(
    const float* __restrict__ facts, const float* __restrict__ questions,
    const float* __restrict__ prevM, const float* __restrict__ z1b,
    const float* __restrict__ z2w, const unsigned short* __restrict__ Bp,
    float* __restrict__ logits) {
  __shared__ float qS[512], mS[512], z1bS[512], z2wS[512];
  __shared__ unsigned short At[64 * 40];
  __shared__ unsigned short Bt[16384];
  __shared__ float lp[64 * 4];
  const int tid = threadIdx.x;
  const int row0 = blockIdx.x * 64;
  const int b = row0 >> 8;
  const int s0 = row0 & 255;
  qS[tid] = questions[b * 512 + tid];
  mS[tid] = prevM[b * 512 + tid];
  z1bS[tid] = z1b[tid];
  z2wS[tid] = z2w[tid];
  const int w = tid >> 6, l = tid & 63;
  const int mgrp = w & 1, ngrp = w >> 1;
  const int lm = l & 15, lk = l >> 4;
  f32x4 acc[2][8];
#pragma unroll
  for (int a = 0; a < 2; ++a)
#pragma unroll
    for (int i = 0; i < 8; ++i) acc[a][i] = (f32x4){0.f, 0.f, 0.f, 0.f};
  const int arow = tid >> 3, ac = tid & 7;
  const float* fbase = facts + ((size_t)(b * 256 + s0 + arow)) * 512 + ac * 4;

  for (int kb = 0; kb < 64; ++kb) {
    __syncthreads();
    const int part = kb >> 4;          // 0: f*q, 1: f*m, 2: |f-q|, 3: |f-m|
    const int h0 = (kb & 15) * 32;
    f32x4 fv = *(const f32x4*)(fbase + h0);
    f32x4 ov = (part & 1) ? *(const f32x4*)&mS[h0 + ac * 4]
                          : *(const f32x4*)&qS[h0 + ac * 4];
    float z0, z1, z2, z3;
    if (part < 2) {
      z0 = fv[0] * ov[0]; z1 = fv[1] * ov[1];
      z2 = fv[2] * ov[2]; z3 = fv[3] * ov[3];
    } else {
      z0 = fabsf(fv[0] - ov[0]); z1 = fabsf(fv[1] - ov[1]);
      z2 = fabsf(fv[2] - ov[2]); z3 = fabsf(fv[3] - ov[3]);
    }
    unsigned p0 = (unsigned)f2bf(z0) | ((unsigned)f2bf(z1) << 16);
    unsigned p1 = (unsigned)f2bf(z2) | ((unsigned)f2bf(z3) << 16);
    u32x2 pk = {p0, p1};
    *(u32x2*)&At[arow * 40 + ac * 4] = pk;
    const char* bsrc = (const char*)Bp + (size_t)kb * 32768;
#pragma unroll
    for (int i = 0; i < 4; ++i)
      *(i32x4*)((char*)Bt + i * 8192 + tid * 16) =
          *(const i32x4*)(bsrc + i * 8192 + tid * 16);
    __syncthreads();
    bf16x8 af[2];
#pragma unroll
    for (int mi = 0; mi < 2; ++mi) {
      i32x4 av = *(const i32x4*)&At[((mgrp * 2 + mi) * 16 + lm) * 40 + lk * 8];
      af[mi] = __builtin_bit_cast(bf16x8, av);
    }
#pragma unroll
    for (int i = 0; i < 8; ++i) {
      const int nt = ngrp * 8 + i;
      i32x4 bv = *(const i32x4*)&Bt[lk * 4096 + (nt * 16 + lm) * 8];
      bf16x8 bf = __builtin_bit_cast(bf16x8, bv);
      acc[0][i] = __builtin_amdgcn_mfma_f32_16x16x32_bf16(af[0], bf, acc[0][i], 0, 0, 0);
      acc[1][i] = __builtin_amdgcn_mfma_f32_16x16x32_bf16(af[1], bf, acc[1][i], 0, 0, 0);
    }
  }
  float pr_[2][4];
#pragma unroll
  for (int mi = 0; mi < 2; ++mi)
#pragma unroll
    for (int r = 0; r < 4; ++r) pr_[mi][r] = 0.f;
#pragma unroll
  for (int i = 0; i < 8; ++i) {
    const int n_i = (ngrp * 8 + i) * 16 + lm;
    const float zb = z1bS[n_i], zw = z2wS[n_i];
#pragma unroll
    for (int mi = 0; mi < 2; ++mi)
#pragma unroll
      for (int r = 0; r < 4; ++r)
        pr_[mi][r] += fast_tanh(acc[mi][i][r] + zb) * zw;
  }
#pragma unroll
  for (int mask = 1; mask < 16; mask <<= 1)
#pragma unroll
    for (int mi = 0; mi < 2; ++mi)
#pragma unroll
      for (int r = 0; r < 4; ++r)
        pr_[mi][r] += __shfl_xor(pr_[mi][r], mask, 64);
  if (lm == 0) {
#pragma unroll
    for (int mi = 0; mi < 2; ++mi)
#pragma unroll
      for (int r = 0; r < 4; ++r)
        lp[((mgrp * 2 + mi) * 16 + lk * 4 + r) * 4 + ngrp] = pr_[mi][r];
  }
  __syncthreads();
  if (tid < 64)
    logits[row0 + tid] =
        lp[tid * 4] + lp[tid * 4 + 1] + lp[tid * 4 + 2] + lp[tid * 4 + 3];
}

// ---------------------------------------------------------------------------
// Softmax over S per batch (z2_b dropped: shift-invariant, exact)
// ---------------------------------------------------------------------------
__global__ void k_softmax(const float* __restrict__ logits,
                          float* __restrict__ G) {
  __shared__ float red[4], red2[4];
  int b = blockIdx.x, t = threadIdx.x;
  float v = logits[b * 256 + t];
  float mx = v;
#pragma unroll
  for (int mask = 1; mask < 64; mask <<= 1)
    mx = fmaxf(mx, __shfl_xor(mx, mask, 64));
  if ((t & 63) == 0) red[t >> 6] = mx;
  __syncthreads();
  mx = fmaxf(fmaxf(red[0], red[1]), fmaxf(red[2], red[3]));
  float e = __expf(v - mx);
  float sm = e;
#pragma unroll
  for (int mask = 1; mask < 64; mask <<= 1) sm += __shfl_xor(sm, mask, 64);
  if ((t & 63) == 0) red2[t >> 6] = sm;
  __syncthreads();
  sm = red2[0] + red2[1] + red2[2] + red2[3];
  G[b * 256 + t] = e / sm;
}

// ---------------------------------------------------------------------------
// Scan v3: 8 groups x 8 member-WGs, 16 batches/group (M=16, no padding).
// WG 'mem' owns n-slice [mem*64, mem*64+64); weights resident in VGPRs.
// Sync: payload-only 8B data stores -> __syncthreads (vmcnt drain) -> one
// flag store per (group,member); consumers poll 7 flags with 7 lanes of
// wave 0 (s_sleep backoff), then one-shot gather. EX parity double-buffered;
// flags monotone (memset 0 per launch). ~7 fabric tx per poll round vs 4096.
// ---------------------------------------------------------------------------
__global__ __launch_bounds__(512, 1) void k_scan(
    const float* __restrict__ facts, const float* __restrict__ Gm,
    const unsigned short* __restrict__ PB, const float* __restrict__ rsr,
    const float* __restrict__ rsh, const float* __restrict__ br,
    const float* __restrict__ bur, const float* __restrict__ bw,
    const float* __restrict__ bu, u64* __restrict__ EXq,
    unsigned int* __restrict__ FLG, float* __restrict__ Cb) {
  __shared__ unsigned short A[16 * 520];  // 16 rows x 512 bf16, 1040B pitch
  __shared__ float outb[8 * 272];         // [w][row16 pitch17], pad vs conflicts
  const int tid = threadIdx.x;
  const int g = blockIdx.x & 7;    // group (same XCD under %8 round-robin)
  const int mem = blockIdx.x >> 3; // member / n-slice owner
  const int w = tid >> 6, l = tid & 63;
  const int lm = l & 15, lk = (l >> 4) & 3;
  // zero A
  for (int i = tid; i < 16 * 520 / 4; i += 512) ((u64*)A)[i] = 0ull;
  // weight fragments resident in VGPRs: this wave = (mat = w>>2, nt = w&3)
  i32x4 bfr[16];
  const char* pb = (const char*)PB + (size_t)(mem * 8 + w) * 16384;
#pragma unroll
  for (int kt = 0; kt < 16; ++kt)
    bfr[kt] = *(const i32x4*)(pb + kt * 1024 + l * 16);
  // elementwise lane (tid<256): thread owns (bb, 4 consecutive n)
  const int bb = tid >> 4;          // 0..15 (only meaningful for tid<256)
  const int nq = tid & 15;          // n-quad within slice
  const int n0 = mem * 64 + nq * 4; // global n base
  const int batch = g * 16 + bb;
  f32x4 c_rsr, c_br, c_rsh, c_bw, c_bur, c_bu;
  const float* fptr = nullptr;
  const float* gptr = nullptr;
  if (tid < 256) {
    c_rsr = *(const f32x4*)(rsr + n0);
    c_br  = *(const f32x4*)(br + n0);
    c_rsh = *(const f32x4*)(rsh + n0);
    c_bw  = *(const f32x4*)(bw + n0);
    c_bur = *(const f32x4*)(bur + n0);
    c_bu  = *(const f32x4*)(bu + n0);
    fptr = facts + (size_t)batch * 256 * 512 + n0;
    gptr = Gm + batch * 256;
  }
  const int pollmem = (tid < mem) ? tid : tid + 1;  // lanes 0..6 -> 7 remotes
  f32x4 Cv = (f32x4){0.f, 0.f, 0.f, 0.f};
  __syncthreads();

  for (int s = 0; s < 256; ++s) {
    const unsigned tag = (unsigned)(s + 1);
    const unsigned base = ((unsigned)(s & 1) * 8 + (unsigned)g) * 2048;
    // prefetch elementwise inputs (overlap with MFMA)
    f32x4 fct;
    float gval = 0.f;
    if (tid < 256) {
      fct = *(const f32x4*)(fptr + (size_t)s * 512);
      gval = gptr[s];
    }
    // ---- matvec: (C @ Ur | C @ U) slice via MFMA, two ILP chains ----
    f32x4 acc0 = (f32x4){0.f, 0.f, 0.f, 0.f};
    f32x4 acc1 = (f32x4){0.f, 0.f, 0.f, 0.f};
#pragma unroll
    for (int kt = 0; kt < 16; ++kt) {
      i32x4 av = *(const i32x4*)&A[lm * 520 + kt * 32 + lk * 8];
      bf16x8 afv = __builtin_bit_cast(bf16x8, av);
      bf16x8 bfv = __builtin_bit_cast(bf16x8, bfr[kt]);
      if (kt & 1)
        acc1 = __builtin_amdgcn_mfma_f32_16x16x32_bf16(afv, bfv, acc1, 0, 0, 0);
      else
        acc0 = __builtin_amdgcn_mfma_f32_16x16x32_bf16(afv, bfv, acc0, 0, 0, 0);
    }
    f32x4 accs = acc0 + acc1;
#pragma unroll
    for (int r = 0; r < 4; ++r)
      outb[w * 272 + (lk * 4 + r) * 17 + lm] = accs[r];
    __syncthreads();  // outb ready; also A MFMA-reads done
    // ---- elementwise update + publish (tid<256; thread owns (bb, n0..n0+3))
    if (tid < 256) {
      unsigned short pk[4];
#pragma unroll
      for (int r = 0; r < 4; ++r) {
        const int n_loc = nq * 4 + r;
        const float uro = outb[(n_loc >> 4) * 272 + bb * 17 + (n_loc & 15)];
        const float uuo = outb[(4 + (n_loc >> 4)) * 272 + bb * 17 + (n_loc & 15)];
        const float pr = fct[r] * c_rsr[r] + c_br[r];
        const float ph = fct[r] * c_rsh[r] + c_bw[r];
        const float r_ = fast_sigmoid(pr + uro + c_bur[r]);
        const float ht = fast_tanh(ph + r_ * (uuo + c_bu[r]));
        Cv[r] = gval * ht + (1.0f - gval) * Cv[r];
        pk[r] = f2bf(Cv[r]);
      }
      const u64 word = (u64)pk[0] | ((u64)pk[1] << 16) | ((u64)pk[2] << 32) |
                       ((u64)pk[3] << 48);
      // own slice straight into A-LDS
      *(u64*)((char*)A + bb * 1040 + n0 * 2) = word;
      // publish payload for the other 7 members
      __hip_atomic_store(EXq + base + (unsigned)bb * 128 + (unsigned)(n0 >> 2),
                         word, __ATOMIC_RELAXED, __HIP_MEMORY_SCOPE_AGENT);
    }
    __syncthreads();  // per-thread vmcnt(0): all data stores drained
    if (tid == 0)
      __hip_atomic_store(FLG + g * 8 + mem, tag, __ATOMIC_RELAXED,
                         __HIP_MEMORY_SCOPE_AGENT);
    // ---- poll 7 remote flags (wave 0, lanes 0..6) with backoff ----
    if (tid < 7) {
      int guard = 0;
      for (;;) {
        unsigned v = __hip_atomic_load(FLG + g * 8 + pollmem, __ATOMIC_RELAXED,
                                       __HIP_MEMORY_SCOPE_AGENT);
        if (v >= tag) break;
        __builtin_amdgcn_s_sleep(1);
        if (++guard > (1 << 22)) break;  // hang-safety bailout
      }
    }
    __syncthreads();  // all 7 remote slices are published & visible
    // ---- one-shot gather: 4 x 8B per thread (32B contiguous) ----
    const u64* srcq = EXq + base;
#pragma unroll
    for (int i = 0; i < 4; ++i) {
      const int u = tid * 4 + i;   // 0..2047 = bb(4b) x n-unit(7b)
      const int nu = u & 127;      // 8B unit within row (n = nu*4)
      if ((nu >> 4) != mem) {
        u64 wv = __hip_atomic_load(srcq + u, __ATOMIC_RELAXED,
                                   __HIP_MEMORY_SCOPE_AGENT);
        *(u64*)((char*)A + (u >> 7) * 1040 + nu * 8) = wv;
      }
    }
    __syncthreads();  // A fully assembled for next step
  }
  if (tid < 256) *(f32x4*)(Cb + (size_t)batch * 512 + n0) = Cv;
}

// ---------------------------------------------------------------------------
// Final: out[b] = relu([prevM | C | questions] @ nm_w + nm_b). 2 batches/WG.
// ---------------------------------------------------------------------------
__global__ __launch_bounds__(512) void k_final(
    const float* __restrict__ prevM, const float* __restrict__ questions,
    const float* __restrict__ Cb, const float* __restrict__ nmw,
    const float* __restrict__ nmb, float* __restrict__ out) {
  __shared__ float cc[2][1536];
  const int t = threadIdx.x;
  const int b0 = blockIdx.x * 2;
  for (int i = t; i < 1536; i += 512) {
#pragma unroll
    for (int bi = 0; bi < 2; ++bi) {
      int bbx = b0 + bi;
      float v;
      if (i < 512) v = prevM[bbx * 512 + i];
      else if (i < 1024) v = Cb[bbx * 512 + i - 512];
      else v = questions[bbx * 512 + i - 1024];
      cc[bi][i] = v;
    }
  }
  __syncthreads();
  const int h = t;
  float a0 = nmb[h], a1 = nmb[h];
#pragma unroll 4
  for (int f = 0; f < 1536; ++f) {
    float wv = nmw[f * 512 + h];
    a0 = fmaf(cc[0][f], wv, a0);
    a1 = fmaf(cc[1][f], wv, a1);
  }
  out[(size_t)b0 * 512 + h] = fmaxf(a0, 0.f);
  out[(size_t)(b0 + 1) * 512 + h] = fmaxf(a1, 0.f);
}

// ---------------------------------------------------------------------------
extern "C" void kernel_launch(void* const* d_in, const int* in_sizes, int n_in,
                              void* d_out, int out_size, void* d_ws,
                              size_t ws_size, hipStream_t stream) {
  const float* facts     = (const float*)d_in[0];
  const float* questions = (const float*)d_in[1];
  const float* prevM     = (const float*)d_in[2];
  const float* z1w       = (const float*)d_in[3];
  const float* z1b       = (const float*)d_in[4];
  const float* z2w       = (const float*)d_in[5];
  // d_in[6] = z2_b: softmax shift-invariant, unused (exact)
  const float* Wr        = (const float*)d_in[7];
  const float* br        = (const float*)d_in[8];
  const float* Ur        = (const float*)d_in[9];
  const float* bur       = (const float*)d_in[10];
  const float* W         = (const float*)d_in[11];
  const float* bw        = (const float*)d_in[12];
  const float* U         = (const float*)d_in[13];
  const float* bu        = (const float*)d_in[14];
  const float* nmw       = (const float*)d_in[15];
  const float* nmb       = (const float*)d_in[16];

  char* ws = (char*)d_ws;
  float* G             = (float*)(ws + OFF_G);
  float* rsr           = (float*)(ws + OFF_RSR);
  float* rsh           = (float*)(ws + OFF_RSH);
  unsigned* FLG        = (unsigned*)(ws + OFF_FLG);
  u64* EXq             = (u64*)(ws + OFF_EX);
  float* Cb            = (float*)(ws + OFF_CBUF);
  float* logits        = (float*)(ws + OFF_LOGITS);
  unsigned short* Bp   = (unsigned short*)(ws + OFF_BP);
  unsigned short* PB   = (unsigned short*)(ws + OFF_PB);

  hipMemsetAsync(FLG, 0, 64 * sizeof(unsigned), stream);
  k_prep_bp<<<2048, 512, 0, stream>>>(z1w, Bp);
  k_prep_pb<<<1024, 512, 0, stream>>>(Ur, U, PB);
  k_prep_rs<<<1024, 256, 0, stream>>>(Wr, W, rsr, rsh);
  k_gate<<<512, 512, 0, stream>>>(facts, questions, prevM, z1b, z2w, Bp, logits);
  k_softmax<<<128, 256, 0, stream>>>(logits, G);
  k_scan<<<64, 512, 0, stream>>>(facts, G, PB, rsr, rsh, br, bur, bw, bu, EXq,
                                 FLG, Cb);
  k_final<<<64, 512, 0, stream>>>(prevM, questions, Cb, nmw, nmb, (float*)d_out);
}